// Round 7
// baseline (508.903 us; speedup 1.0000x reference)
//
#include <hip/hip_runtime.h>
#include <hip/hip_bf16.h>

// SphereConv N=2, CIN=64, COUT=64, H=256, W=512, K2=9.
// Round 10: interpolate THROUGH the MFMA. Record: R7(8 waves)=168us ~=
// R9(16 waves)=175us, traffic-insensitive, all pipes <31% -> per-wave
// SERIAL stall (~7k cyc/step vs ~600 busy). The serial segment is the
// interp chain (unpack->16 chained pk_fma->cvt->pack) + 24KB unrolled body.
// Fix via linearity: sum_c w_c (W . x_c) == W . (sum_c w_c x_c). Corner
// weight w_c is per-pixel = per-D-column = per-lane -> feed RAW gathered
// bf16 corners as B-frags (gather result IS the fragment; zero unpack/
// cvt/pack), 4x MFMA per k-slice (C=0), then acc += w_c * D (f32 pk_fma).
// Per tap: ~300 VALU (no chains) + 64 MFMA (idle pipe) + same 28 VMEM.
// Loop ROLLED (2x-unrolled, ~6KB body, icache-resident), pos 2 taps ahead,
// gathers 1 tap ahead. ~200 VGPR -> 2 waves/SIMD (R7 proved sufficient).
// Numerics improve: no bf16 rounding of interpolated values.

constexpr int N_ = 2;
constexpr int CIN = 64;
constexpr int COUT = 64;
constexpr int H_ = 256;
constexpr int W_ = 512;
constexpr int K2 = 9;
constexpr int HW = H_ * W_;
constexpr int NSTEP = (CIN * K2) / 32;  // 18
constexpr int PTILE = 128;
constexpr int OROW = 36;  // epilogue LDS row stride (floats); 144 B

typedef __attribute__((ext_vector_type(8))) short short8;
typedef __attribute__((ext_vector_type(4))) float floatx4;

// wTr[(ot*18 + s)*64*8 + lane*8 + j] = bf16(weight[o = 16*ot + (lane&15)]
//                                           [kk = 32s + (lane>>4)*8 + j])
__global__ void prep_w(const float* __restrict__ w, ushort* __restrict__ wTr) {
  int i = blockIdx.x * blockDim.x + threadIdx.x;
  if (i >= 4 * NSTEP * 64 * 8) return;
  int j = i & 7;
  int lane = (i >> 3) & 63;
  int s = (i >> 9) % NSTEP;
  int ot = i / (512 * NSTEP);
  int o = ot * 16 + (lane & 15);
  int kk = s * 32 + (lane >> 4) * 8 + j;
  int tap = kk >> 6, c = kk & 63;
  __hip_bfloat16 b = __float2bfloat16(w[(o * CIN + c) * K2 + tap]);
  wTr[i] = *(ushort*)&b;
}

// x[n][c][hw] fp32 -> xt[n][hw][c] bf16, via LDS tile (64 px x 64 ch).
__global__ __launch_bounds__(256) void transpose_x(
    const float* __restrict__ x, ushort* __restrict__ xt) {
  __shared__ ushort tile[64 * 72];
  int b = blockIdx.x;
  int n = b >> 11;
  int hw0 = (b & 2047) * 64;
  int tid = threadIdx.x;
  int px = tid & 63, c4 = tid >> 6;
  const float* xn = x + (size_t)n * CIN * HW;
#pragma unroll
  for (int it = 0; it < 16; ++it) {
    int c = it * 4 + c4;
    float v = xn[(size_t)c * HW + hw0 + px];
    __hip_bfloat16 hb = __float2bfloat16(v);
    tile[px * 72 + c] = *(ushort*)&hb;
  }
  __syncthreads();
  ushort* xtn = xt + (size_t)n * HW * CIN;
#pragma unroll
  for (int it = 0; it < 2; ++it) {
    int task = it * 256 + tid;
    int px2 = task >> 3, chunk = task & 7;
    uint4 v = *(uint4*)&tile[px2 * 72 + chunk * 8];
    *(uint4*)&xtn[(size_t)(hw0 + px2) * 64 + chunk * 8] = v;
  }
}

__global__ __launch_bounds__(256, 2) void sphere_conv_mfma(
    const ushort* __restrict__ xt, const ushort* __restrict__ wTr,
    const float* __restrict__ pos, float* __restrict__ out) {
  __shared__ float lds_o[4][64 * OROW];  // 36.9 KB epilogue bounce

  int tid = threadIdx.x;
  // XCD-chunked swizzle: 2048 blocks = 8 chunks x 256.
  int orig = blockIdx.x;
  int blk = (orig & 7) * 256 + (orig >> 3);
  int n = blk >> 10;
  int ptile = (blk & 1023) * PTILE;
  int lane = tid & 63, wv = tid >> 6;
  int col = lane & 15, quad = lane >> 4;

  int hw0 = ptile + wv * 32 + col;
  int hw1 = hw0 + 16;

  const ushort* xtn = xt + (size_t)n * HW * CIN;

  floatx4 acc[2][4];
#pragma unroll
  for (int T = 0; T < 2; ++T)
#pragma unroll
    for (int ot = 0; ot < 4; ++ot) acc[T][ot] = (floatx4)0.f;

  // pipeline state
  float pyC[2], pxC[2];  // pos of the NEXT tap (params source)
  float pyN[2], pxN[2];  // pos of tap after that (in flight)
  float w4C[2][4];       // corner weights of CURRENT tap (scale-add)
  float w4N[2][4];       // corner weights of next tap (just computed)
  int o00N[2], dxoN[2], dyoN[2];  // gather offsets for next tap

  auto loadPosTo = [&](int t, float (&py)[2], float (&px)[2]) {
    py[0] = pos[(2 * t + 0) * HW + hw0];
    px[0] = pos[(2 * t + 1) * HW + hw0];
    py[1] = pos[(2 * t + 0) * HW + hw1];
    px[1] = pos[(2 * t + 1) * HW + hw1];
  };

  auto calcParamsN = [&]() {
#pragma unroll
    for (int T = 0; T < 2; ++T) {
      float py = pyC[T], pxx = pxC[T];
      float y0f = floorf(py), x0f = floorf(pxx);
      float dy = py - y0f, dx = pxx - x0f;
      float y1f = y0f + 1.f, x1f = x0f + 1.f;
      float vy0 = (y0f >= 0.f && y0f <= (float)(H_ - 1)) ? 1.f : 0.f;
      float vy1 = (y1f >= 0.f && y1f <= (float)(H_ - 1)) ? 1.f : 0.f;
      float vx0 = (x0f >= 0.f && x0f <= (float)(W_ - 1)) ? 1.f : 0.f;
      float vx1 = (x1f >= 0.f && x1f <= (float)(W_ - 1)) ? 1.f : 0.f;
      w4N[T][0] = (1.f - dy) * (1.f - dx) * vy0 * vx0;
      w4N[T][1] = (1.f - dy) * dx * vy0 * vx1;
      w4N[T][2] = dy * (1.f - dx) * vy1 * vx0;
      w4N[T][3] = dy * dx * vy1 * vx1;
      int y0c = (int)fminf(fmaxf(y0f, 0.f), (float)(H_ - 1));
      int y1c = (int)fminf(fmaxf(y1f, 0.f), (float)(H_ - 1));
      int x0c = (int)fminf(fmaxf(x0f, 0.f), (float)(W_ - 1));
      int x1c = (int)fminf(fmaxf(x1f, 0.f), (float)(W_ - 1));
      o00N[T] = (y0c * W_ + x0c) * CIN;
      dxoN[T] = (x1c - x0c) * CIN;
      dyoN[T] = (y1c - y0c) * (W_ * CIN);
    }
  };

  // raw corner gathers for one K=32 slice; g[c][T] IS the B-fragment.
  auto gatherKK = [&](int kk, short8 (&g)[4][2]) {
    int co = (kk << 5) + (quad << 3);
#pragma unroll
    for (int T = 0; T < 2; ++T) {
      const ushort* p00 = xtn + (size_t)o00N[T] + co;
      const ushort* p10 = p00 + dyoN[T];
      g[0][T] = *(const short8*)p00;
      g[1][T] = *(const short8*)(p00 + dxoN[T]);
      g[2][T] = *(const short8*)p10;
      g[3][T] = *(const short8*)(p10 + dxoN[T]);
    }
  };

  auto loadAfr = [&](int t, int kk, short8 (&afr)[4]) {
#pragma unroll
    for (int ot = 0; ot < 4; ++ot)
      afr[ot] = *(const short8*)(wTr +
                 ((size_t)(ot * NSTEP + 2 * t + kk) * 64 + lane) * 8);
  };

  // per corner: D = W_slice . X_corner (C=0), acc += w_c * D  (f32)
  auto mfmaHalf = [&](short8 (&afr)[4], short8 (&g)[4][2]) {
#pragma unroll
    for (int c = 0; c < 4; ++c) {
#pragma unroll
      for (int T = 0; T < 2; ++T) {
        floatx4 wc = {w4C[T][c], w4C[T][c], w4C[T][c], w4C[T][c]};
#pragma unroll
        for (int ot = 0; ot < 4; ++ot) {
          floatx4 D = __builtin_amdgcn_mfma_f32_16x16x32_bf16(
              afr[ot], g[c][T], (floatx4)0.f, 0, 0, 0);
          acc[T][ot] = __builtin_elementwise_fma(wc, D, acc[T][ot]);
        }
      }
    }
  };

  short8 Ga0[4][2], Ga1[4][2], Gb0[4][2], Gb1[4][2];

  // ---- prologue: params(0) + gathers(0); leave pos(1) in posC ----
  loadPosTo(0, pyC, pxC);
  calcParamsN();  // one exposed pos latency, once per block
#pragma unroll
  for (int T = 0; T < 2; ++T)
#pragma unroll
    for (int c = 0; c < 4; ++c) w4C[T][c] = w4N[T][c];
  gatherKK(0, Ga0);
  gatherKK(1, Ga1);
  loadPosTo(1, pyC, pxC);

#define ITER(t, GC0, GC1, GN0, GN1)                                 \
  {                                                                 \
    if ((t) + 2 <= K2 - 1) loadPosTo((t) + 2, pyN, pxN);            \
    short8 afr0[4], afr1[4];                                        \
    loadAfr((t), 0, afr0);                                          \
    loadAfr((t), 1, afr1);                                          \
    if ((t) + 1 <= K2 - 1) calcParamsN();                           \
    mfmaHalf(afr0, GC0);                                            \
    if ((t) + 1 <= K2 - 1) gatherKK(0, GN0);                        \
    mfmaHalf(afr1, GC1);                                            \
    if ((t) + 1 <= K2 - 1) gatherKK(1, GN1);                        \
    pyC[0] = pyN[0]; pyC[1] = pyN[1];                               \
    pxC[0] = pxN[0]; pxC[1] = pxN[1];                               \
    _Pragma("unroll")                                               \
    for (int T = 0; T < 2; ++T)                                     \
      _Pragma("unroll")                                             \
      for (int c = 0; c < 4; ++c) w4C[T][c] = w4N[T][c];            \
  }

  // rolled (icache-resident), 2x-unrolled so buffer rotation is free
#pragma unroll 1
  for (int th = 0; th < 4; ++th) {
    int t0 = 2 * th;
    ITER(t0, Ga0, Ga1, Gb0, Gb1);
    ITER(t0 + 1, Gb0, Gb1, Ga0, Ga1);
  }
  ITER(8, Ga0, Ga1, Gb0, Gb1);
#undef ITER

  // ---- epilogue: per-wave LDS bounce -> full-line float4 stores ----
  float* lo = lds_o[wv];
#pragma unroll
  for (int T = 0; T < 2; ++T)
#pragma unroll
    for (int ot = 0; ot < 4; ++ot)
#pragma unroll
      for (int r = 0; r < 4; ++r)
        lo[(ot * 16 + quad * 4 + r) * OROW + T * 16 + col] = acc[T][ot][r];
#pragma unroll
  for (int it = 0; it < 2; ++it) {
    int task = it * 64 + lane;
    int o = task >> 1, half = task & 1;
    const float* src = &lo[o * OROW + half * 16];
    float4 v0 = *(const float4*)(src + 0);
    float4 v1 = *(const float4*)(src + 4);
    float4 v2 = *(const float4*)(src + 8);
    float4 v3 = *(const float4*)(src + 12);
    float* dst = &out[(size_t)(n * COUT + o) * HW + ptile + wv * 32 + half * 16];
    *(float4*)(dst + 0) = v0;
    *(float4*)(dst + 4) = v1;
    *(float4*)(dst + 8) = v2;
    *(float4*)(dst + 12) = v3;
  }
}

extern "C" void kernel_launch(void* const* d_in, const int* in_sizes, int n_in,
                              void* d_out, int out_size, void* d_ws, size_t ws_size,
                              hipStream_t stream) {
  const float* x   = (const float*)d_in[0];  // (2, 64, 256, 512) fp32
  const float* w   = (const float*)d_in[1];  // (64, 64, 3, 3) fp32
  const float* pos = (const float*)d_in[2];  // (18, 256, 512) fp32
  float* out = (float*)d_out;                // (2, 64, 256, 512) fp32

  // ws layout: wTr bf16 [72 KB] at 0; xt bf16 [33.6 MB] at 128 KB.
  ushort* wTr = (ushort*)d_ws;
  ushort* xt = (ushort*)((char*)d_ws + (128 << 10));

  prep_w<<<(4 * NSTEP * 64 * 8 + 255) / 256, 256, 0, stream>>>(w, wTr);
  transpose_x<<<N_ * (HW / 64), 256, 0, stream>>>(x, xt);

  int nblk = N_ * (HW / PTILE);  // 2048
  sphere_conv_mfma<<<nblk, 256, 0, stream>>>(xt, wTr, pos, out);
}

// Round 8
// 209.696 us; speedup vs baseline: 2.4269x; 2.4269x over previous
//
#include <hip/hip_runtime.h>
#include <hip/hip_bf16.h>

// SphereConv N=2, CIN=64, COUT=64, H=256, W=512, K2=9.
// Round 11: revert to the session-best lockstep baseline (135us main kernel:
// double-buffered sbuf, 1 barrier/step, register prefetch, pk_fma interp,
// bf16 interp weights in LDS) + the ONE lever proven isolated-positive this
// session: XCD-chunked block swizzle (R5->R6: FETCH 303->35MB). R10's
// through-MFMA rewrite spilled (4 live gather buffers + acc > reg budget,
// FETCH 497MB scratch traffic) and R8's occupancy push spilled likewise —
// both invalidated their theories. Lockstep + swizzle is the only untested
// combination of known-good parts.

constexpr int N_ = 2;
constexpr int CIN = 64;
constexpr int COUT = 64;
constexpr int H_ = 256;
constexpr int W_ = 512;
constexpr int K2 = 9;
constexpr int HW = H_ * W_;
constexpr int NSTEP = (CIN * K2) / 32;  // 18
constexpr int PTILE = 128;
constexpr int SROW = 40;  // sbuf row stride (32 + 8 pad, keeps 16B align)

typedef __attribute__((ext_vector_type(8))) short short8;
typedef __attribute__((ext_vector_type(4))) float floatx4;
typedef __attribute__((ext_vector_type(2))) float floatx2;

__device__ __forceinline__ float bfhi2f(unsigned u) {  // already-positioned bits
  return __uint_as_float(u);
}

// wTr[(wv*18 + s)*64*8 + lane*8 + j] = bf16(weight[o = 16wv + (lane&15)]
//                                           [kk = 32s + (lane>>4)*8 + j])
__global__ void prep_w(const float* __restrict__ w, ushort* __restrict__ wTr) {
  int i = blockIdx.x * blockDim.x + threadIdx.x;
  if (i >= 4 * NSTEP * 64 * 8) return;
  int j = i & 7;
  int lane = (i >> 3) & 63;
  int s = (i >> 9) % NSTEP;
  int wv = i / (512 * NSTEP);
  int o = wv * 16 + (lane & 15);
  int kk = s * 32 + (lane >> 4) * 8 + j;
  int tap = kk >> 6, c = kk & 63;
  __hip_bfloat16 b = __float2bfloat16(w[(o * CIN + c) * K2 + tap]);
  wTr[i] = *(ushort*)&b;
}

// x[n][c][hw] fp32 -> xt[n][hw][c] bf16, via LDS tile (64 px x 64 ch).
__global__ __launch_bounds__(256) void transpose_x(
    const float* __restrict__ x, ushort* __restrict__ xt) {
  __shared__ ushort tile[64 * 72];
  int b = blockIdx.x;
  int n = b >> 11;
  int hw0 = (b & 2047) * 64;
  int tid = threadIdx.x;
  int px = tid & 63, c4 = tid >> 6;
  const float* xn = x + (size_t)n * CIN * HW;
#pragma unroll
  for (int it = 0; it < 16; ++it) {
    int c = it * 4 + c4;
    float v = xn[(size_t)c * HW + hw0 + px];
    __hip_bfloat16 hb = __float2bfloat16(v);
    tile[px * 72 + c] = *(ushort*)&hb;
  }
  __syncthreads();
  ushort* xtn = xt + (size_t)n * HW * CIN;
#pragma unroll
  for (int it = 0; it < 2; ++it) {
    int task = it * 256 + tid;
    int px2 = task >> 3, chunk = task & 7;
    uint4 v = *(uint4*)&tile[px2 * 72 + chunk * 8];
    *(uint4*)&xtn[(size_t)(hw0 + px2) * 64 + chunk * 8] = v;
  }
}

__global__ __launch_bounds__(256, 3) void sphere_conv_mfma(
    const ushort* __restrict__ xt, const ushort* __restrict__ wTr,
    const float* __restrict__ pos, float* __restrict__ out) {
  __shared__ int off_lds[K2 * PTILE];          // 4.6 KB packed o00|dx<<20|dy<<21
  __shared__ uint2 wgt_lds[K2 * PTILE];        // 9.2 KB: 4 corner wgts in bf16
  __shared__ ushort sbuf[2][PTILE * SROW];     // 20 KB: double-buffered S tile

  int tid = threadIdx.x;
  // XCD-chunked swizzle (proven R5->R6): 2048 blocks = 8 chunks x 256.
  int orig = blockIdx.x;
  int blk = (orig & 7) * 256 + (orig >> 3);
  int n = blk >> 10;
  int ptile = (blk & 1023) * PTILE;

  // ---- phase 0: bilinear offsets/weights for 9 taps x 128 pixels ----
  for (int i = tid; i < K2 * PTILE; i += 256) {
    int t = i / PTILE, p = i - t * PTILE;
    int hw = ptile + p;
    float py = pos[(2 * t + 0) * HW + hw];
    float px = pos[(2 * t + 1) * HW + hw];
    float y0f = floorf(py), x0f = floorf(px);
    float dy = py - y0f, dx = px - x0f;
    float y1f = y0f + 1.f, x1f = x0f + 1.f;
    float vy0 = (y0f >= 0.f && y0f <= (float)(H_ - 1)) ? 1.f : 0.f;
    float vy1 = (y1f >= 0.f && y1f <= (float)(H_ - 1)) ? 1.f : 0.f;
    float vx0 = (x0f >= 0.f && x0f <= (float)(W_ - 1)) ? 1.f : 0.f;
    float vx1 = (x1f >= 0.f && x1f <= (float)(W_ - 1)) ? 1.f : 0.f;
    float w00 = (1.f - dy) * (1.f - dx) * vy0 * vx0;
    float w01 = (1.f - dy) * dx * vy0 * vx1;
    float w10 = dy * (1.f - dx) * vy1 * vx0;
    float w11 = dy * dx * vy1 * vx1;
    int y0c = (int)fminf(fmaxf(y0f, 0.f), (float)(H_ - 1));
    int y1c = (int)fminf(fmaxf(y1f, 0.f), (float)(H_ - 1));
    int x0c = (int)fminf(fmaxf(x0f, 0.f), (float)(W_ - 1));
    int x1c = (int)fminf(fmaxf(x1f, 0.f), (float)(W_ - 1));
    int o00 = y0c * W_ + x0c;
    off_lds[i] = o00 | ((x1c - x0c) << 20) | ((y1c - y0c) << 21);
    __hip_bfloat16 b00 = __float2bfloat16(w00), b01 = __float2bfloat16(w01);
    __hip_bfloat16 b10 = __float2bfloat16(w10), b11 = __float2bfloat16(w11);
    unsigned lo = ((unsigned)*(ushort*)&b01 << 16) | *(ushort*)&b00;
    unsigned hi = ((unsigned)*(ushort*)&b11 << 16) | *(ushort*)&b10;
    wgt_lds[i] = make_uint2(lo, hi);
  }

  int lane = tid & 63, wv = tid >> 6;
  int col = lane & 15, quad = lane >> 4;
  int px_s = tid >> 1, hf = tid & 1;  // sampling: pixel, channel-16 half

  floatx4 acc[8];
#pragma unroll
  for (int nt = 0; nt < 8; ++nt) acc[nt] = (floatx4)0.f;

  const ushort* xtn = xt + (size_t)n * HW * CIN;

  __syncthreads();

  // stage-load: off/wgt decode + 8 gather loads for step s
  auto gather = [&](int s, short8 g[8], float w4[4]) {
    int t = s >> 1;
    int c0 = ((s & 1) << 5) + (hf << 4);
    int pk = off_lds[t * PTILE + px_s];
    uint2 wr = wgt_lds[t * PTILE + px_s];
    w4[0] = bfhi2f(wr.x << 16);
    w4[1] = bfhi2f(wr.x & 0xFFFF0000u);
    w4[2] = bfhi2f(wr.y << 16);
    w4[3] = bfhi2f(wr.y & 0xFFFF0000u);
    int o00 = pk & 0x1FFFF;
    int dx1 = (pk >> 20) & 1;
    int dyW = ((pk >> 21) & 1) * W_;
    const ushort* base = xtn + c0;
    const ushort* p00 = base + (size_t)o00 * 64;
    const ushort* p01 = p00 + dx1 * 64;
    const ushort* p10 = p00 + dyW * 64;
    const ushort* p11 = p10 + dx1 * 64;
    g[0] = *(const short8*)p00; g[1] = *(const short8*)(p00 + 8);
    g[2] = *(const short8*)p01; g[3] = *(const short8*)(p01 + 8);
    g[4] = *(const short8*)p10; g[5] = *(const short8*)(p10 + 8);
    g[6] = *(const short8*)p11; g[7] = *(const short8*)(p11 + 8);
  };

  short8 gA[8];
  float wA[4];
  gather(0, gA, wA);

#pragma unroll
  for (int s = 0; s < NSTEP; ++s) {
    short8 gB[8];
    float wB[4];
    if (s + 1 < NSTEP) gather(s + 1, gB, wB);  // prefetch next stage

    // ---- interp current stage (pk f32 math), write sbuf[s&1] ----
    const unsigned* u = (const unsigned*)gA;  // 32 dwords: corner c at u[8c+d]
    floatx2 a2[8];
#pragma unroll
    for (int d = 0; d < 8; ++d) {
      floatx2 f = {bfhi2f(u[d] << 16), bfhi2f(u[d] & 0xFFFF0000u)};
      a2[d] = floatx2{wA[0], wA[0]} * f;
    }
#pragma unroll
    for (int c = 1; c < 4; ++c) {
#pragma unroll
      for (int d = 0; d < 8; ++d) {
        unsigned v = u[c * 8 + d];
        floatx2 f = {bfhi2f(v << 16), bfhi2f(v & 0xFFFF0000u)};
        a2[d] = __builtin_elementwise_fma(floatx2{wA[c], wA[c]}, f, a2[d]);
      }
    }
    __align__(16) unsigned tmp[8];
#pragma unroll
    for (int d = 0; d < 8; ++d) {
      __hip_bfloat16 lo = __float2bfloat16(a2[d].x);
      __hip_bfloat16 hi = __float2bfloat16(a2[d].y);
      tmp[d] = ((unsigned)*(ushort*)&hi << 16) | *(ushort*)&lo;
    }
    uint4* dst = (uint4*)&sbuf[s & 1][px_s * SROW + hf * 16];
    dst[0] = ((const uint4*)tmp)[0];
    dst[1] = ((const uint4*)tmp)[1];

    __syncthreads();  // single barrier: write(s) before read(s); write(s+2)
                      // to same buffer is fenced by barrier(s+1).

    short8 afrag = *(const short8*)(wTr + ((wv * NSTEP + s) * 64 + lane) * 8);
#pragma unroll
    for (int nt = 0; nt < 8; ++nt) {
      short8 bfrag = *(const short8*)&sbuf[s & 1][(nt * 16 + col) * SROW + quad * 8];
      acc[nt] = __builtin_amdgcn_mfma_f32_16x16x32_bf16(afrag, bfrag, acc[nt], 0, 0, 0);
    }

    if (s + 1 < NSTEP) {
#pragma unroll
      for (int q = 0; q < 8; ++q) gA[q] = gB[q];
#pragma unroll
      for (int q = 0; q < 4; ++q) wA[q] = wB[q];
    }
  }

  // ---- epilogue: D row = quad*4+r (COUT), col = lane&15 (pixel) ----
#pragma unroll
  for (int nt = 0; nt < 8; ++nt) {
#pragma unroll
    for (int r = 0; r < 4; ++r) {
      int o = wv * 16 + quad * 4 + r;
      out[(size_t)(n * COUT + o) * HW + ptile + nt * 16 + col] = acc[nt][r];
    }
  }
}

extern "C" void kernel_launch(void* const* d_in, const int* in_sizes, int n_in,
                              void* d_out, int out_size, void* d_ws, size_t ws_size,
                              hipStream_t stream) {
  const float* x   = (const float*)d_in[0];  // (2, 64, 256, 512) fp32
  const float* w   = (const float*)d_in[1];  // (64, 64, 3, 3) fp32
  const float* pos = (const float*)d_in[2];  // (18, 256, 512) fp32
  float* out = (float*)d_out;                // (2, 64, 256, 512) fp32

  // ws layout: wTr bf16 [72 KB] at 0; xt bf16 [67.1 MB] at 128 KB.
  ushort* wTr = (ushort*)d_ws;
  ushort* xt = (ushort*)((char*)d_ws + (128 << 10));

  prep_w<<<(4 * NSTEP * 64 * 8 + 255) / 256, 256, 0, stream>>>(w, wTr);
  transpose_x<<<N_ * (HW / 64), 256, 0, stream>>>(x, xt);

  int nblk = N_ * (HW / PTILE);  // 2048
  sphere_conv_mfma<<<nblk, 256, 0, stream>>>(xt, wTr, pos, out);
}